// Round 6
// baseline (171.818 us; speedup 1.0000x reference)
//
#include <hip/hip_runtime.h>

// y[b, c, h, w] = x[b, h, w] * kernels[c, h, w]
// B=128, C=32, H=W=224 -> HW = 50176 floats = 12544 float4 per slab.
// R3 structure (4b x 4c per thread, i-fastest / tile-in-y dispatch, NT
// stores) but 7 i-chunks per block: grid (7,256) = 1792 blocks = exactly
// 7 blocks/CU (28 waves/CU), zero tail, one block-wave, 28KB contiguous
// writes per slab per block. __launch_bounds__(256,7) keeps VGPR <= 73 so
// all 7 blocks/CU are co-resident.

#define HW    50176
#define HW4   12544          // HW / 4 (float4 units)
#define CC    32
#define BB    128
#define NB    4              // b's per thread
#define NC    4              // c's per thread
#define CHUNKS 7             // consecutive 256-wide i-chunks per block

typedef float f32x4 __attribute__((ext_vector_type(4)));

__global__ __launch_bounds__(256, 7) void involution_mul_kernel(
    const float* __restrict__ x,
    const float* __restrict__ k,
    float* __restrict__ out)
{
    const int tile = blockIdx.y;                     // 256 tiles
    const int b0 = (tile >> 3) * NB;                 // btile = tile/8 (32 values)
    const int c0 = (tile & 7) * NC;                  // ctile = tile%8 (8 values)
    const int ibase = blockIdx.x * (CHUNKS * 256) + threadIdx.x;

    const f32x4* xp = reinterpret_cast<const f32x4*>(x) + (size_t)b0 * HW4;
    const f32x4* kp = reinterpret_cast<const f32x4*>(k) + (size_t)c0 * HW4;
    f32x4* op = reinterpret_cast<f32x4*>(out) + ((size_t)b0 * CC + c0) * HW4;

#pragma unroll
    for (int ii = 0; ii < CHUNKS; ++ii) {
        const int i = ibase + ii * 256;

        f32x4 xv[NB], kv[NC];
#pragma unroll
        for (int ib = 0; ib < NB; ++ib) xv[ib] = xp[(size_t)ib * HW4 + i];
#pragma unroll
        for (int ic = 0; ic < NC; ++ic) kv[ic] = kp[(size_t)ic * HW4 + i];

#pragma unroll
        for (int ib = 0; ib < NB; ++ib) {
#pragma unroll
            for (int ic = 0; ic < NC; ++ic) {
                f32x4 o = xv[ib] * kv[ic];
                __builtin_nontemporal_store(o, op + ((size_t)ib * CC + ic) * HW4 + i);
            }
        }
    }
}

extern "C" void kernel_launch(void* const* d_in, const int* in_sizes, int n_in,
                              void* d_out, int out_size, void* d_ws, size_t ws_size,
                              hipStream_t stream) {
    const float* x = (const float*)d_in[0];   // [128, 224, 224]
    const float* k = (const float*)d_in[1];   // [32, 224, 224]
    float* out = (float*)d_out;               // [128, 32, 224, 224]

    dim3 grid(CHUNKS, (BB / NB) * (CC / NC));   // (7, 256) = 1792 blocks
    involution_mul_kernel<<<grid, 256, 0, stream>>>(x, k, out);
}

// Round 7
// 153.676 us; speedup vs baseline: 1.1180x; 1.1180x over previous
//
#include <hip/hip_runtime.h>

// y[b, c, h, w] = x[b, h, w] * kernels[c, h, w]
// B=128, C=32, H=W=224 -> HW = 50176 floats = 12544 float4 per slab.
// R3 structure (i-fastest / tile-in-y dispatch, short 1-chunk blocks, NT
// stores) with deeper asymmetric tile: 8b x 4c per thread. Instr-level
// reads 410 -> 308 MB (k reads halve). No launch_bounds min-occupancy cap
// so the 12 loads stay in flight.

#define HW    50176
#define HW4   12544          // HW / 4 (float4 units)
#define CC    32
#define BB    128
#define NB    8              // b's per thread
#define NC    4              // c's per thread

typedef float f32x4 __attribute__((ext_vector_type(4)));

__global__ __launch_bounds__(256) void involution_mul_kernel(
    const float* __restrict__ x,
    const float* __restrict__ k,
    float* __restrict__ out)
{
    const int i    = blockIdx.x * 256 + threadIdx.x; // float4 idx in [0, HW4)
    const int tile = blockIdx.y;                     // 128 tiles: 16 btiles x 8 ctiles
    const int b0 = (tile >> 3) * NB;                 // btile = tile/8 (16 values)
    const int c0 = (tile & 7) * NC;                  // ctile = tile%8 (8 values)

    const f32x4* xp = reinterpret_cast<const f32x4*>(x) + (size_t)b0 * HW4 + i;
    const f32x4* kp = reinterpret_cast<const f32x4*>(k) + (size_t)c0 * HW4 + i;

    f32x4 xv[NB], kv[NC];
#pragma unroll
    for (int ib = 0; ib < NB; ++ib) xv[ib] = xp[(size_t)ib * HW4];
#pragma unroll
    for (int ic = 0; ic < NC; ++ic) kv[ic] = kp[(size_t)ic * HW4];

    f32x4* op = reinterpret_cast<f32x4*>(out) + ((size_t)b0 * CC + c0) * HW4 + i;
#pragma unroll
    for (int ib = 0; ib < NB; ++ib) {
#pragma unroll
        for (int ic = 0; ic < NC; ++ic) {
            f32x4 o = xv[ib] * kv[ic];
            __builtin_nontemporal_store(o, op + ((size_t)ib * CC + ic) * HW4);
        }
    }
}

extern "C" void kernel_launch(void* const* d_in, const int* in_sizes, int n_in,
                              void* d_out, int out_size, void* d_ws, size_t ws_size,
                              hipStream_t stream) {
    const float* x = (const float*)d_in[0];   // [128, 224, 224]
    const float* k = (const float*)d_in[1];   // [32, 224, 224]
    float* out = (float*)d_out;               // [128, 32, 224, 224]

    dim3 grid(HW4 / 256, (BB / NB) * (CC / NC));   // (49, 128)
    involution_mul_kernel<<<grid, 256, 0, stream>>>(x, k, out);
}

// Round 8
// 149.008 us; speedup vs baseline: 1.1531x; 1.0313x over previous
//
#include <hip/hip_runtime.h>

// y[b, c, h, w] = x[b, h, w] * kernels[c, h, w]
// B=128, C=32, H=W=224 -> HW = 50176 floats = 12544 float4 per slab.
// HBM-write-bound (822 MB out, 32 MB in). Register-tile 4b x 4c per thread
// (best of {4x4, 8x4, 8x8}); i-fastest / tile-in-y dispatch (best temporal
// write pattern); nontemporal stores keep L2 clean for the read working set.
// Measured 149.1 us ~= 5.75 TB/s effective vs 6.8 TB/s pure-write memset —
// the mixed read+write DRAM wall. All structural perturbations (tile-in-x,
// XCD c-pinning, block chunking, deeper tiles) regressed 3-15%.

#define HW    50176
#define HW4   12544          // HW / 4 (float4 units)
#define CC    32
#define BB    128
#define NB    4              // b's per thread
#define NC    4              // c's per thread

typedef float f32x4 __attribute__((ext_vector_type(4)));

__global__ __launch_bounds__(256) void involution_mul_kernel(
    const float* __restrict__ x,
    const float* __restrict__ k,
    float* __restrict__ out)
{
    const int i  = blockIdx.x * 256 + threadIdx.x;   // float4 idx in [0, HW4)
    const int ty = blockIdx.y;                       // tile id: 32 b-tiles * 8 c-tiles
    const int b0 = (ty >> 3) * NB;                   // b tile base
    const int c0 = (ty & 7) * NC;                    // c tile base

    const f32x4* xp = reinterpret_cast<const f32x4*>(x) + (size_t)b0 * HW4 + i;
    const f32x4* kp = reinterpret_cast<const f32x4*>(k) + (size_t)c0 * HW4 + i;

    f32x4 xv[NB], kv[NC];
#pragma unroll
    for (int ib = 0; ib < NB; ++ib) xv[ib] = xp[(size_t)ib * HW4];
#pragma unroll
    for (int ic = 0; ic < NC; ++ic) kv[ic] = kp[(size_t)ic * HW4];

    f32x4* op = reinterpret_cast<f32x4*>(out) + ((size_t)b0 * CC + c0) * HW4 + i;
#pragma unroll
    for (int ib = 0; ib < NB; ++ib) {
#pragma unroll
        for (int ic = 0; ic < NC; ++ic) {
            f32x4 o = xv[ib] * kv[ic];
            __builtin_nontemporal_store(o, op + ((size_t)ib * CC + ic) * HW4);
        }
    }
}

extern "C" void kernel_launch(void* const* d_in, const int* in_sizes, int n_in,
                              void* d_out, int out_size, void* d_ws, size_t ws_size,
                              hipStream_t stream) {
    const float* x = (const float*)d_in[0];   // [128, 224, 224]
    const float* k = (const float*)d_in[1];   // [32, 224, 224]
    float* out = (float*)d_out;               // [128, 32, 224, 224]

    dim3 grid(HW4 / 256, (BB / NB) * (CC / NC));   // (49, 256)
    involution_mul_kernel<<<grid, 256, 0, stream>>>(x, k, out);
}